// Round 1
// baseline (358.480 us; speedup 1.0000x reference)
//
#include <hip/hip_runtime.h>
#include <hip/hip_bf16.h>

// MaxUnpooling2D as a pure gather.
// setup_inputs guarantees mask[b,h,w,c] = ((2h+dy)*WOUT + (2w+dx))*C + c with
// dy,dx in {0,1}: every source scatters inside its own 2x2 window, same channel,
// duplicate-free. Therefore output (b,yo,xo,c) = updates[b,yo/2,xo/2,c] iff
// mask[b,yo/2,xo/2,c] == (yo*WOUT+xo)*C + c, else 0. One pass, every output
// element written exactly once (handles the 0xAA-poisoned d_out), no atomics,
// no zero-init kernel.
//
// Shapes (all powers of 2): B=8, H=W=128, C=128, HOUT=WOUT=256.
// Within-batch output offset of window corner (2h,2w,c) = h<<16 | w<<8 | c,
// identical to the mask flat-index encoding. Window neighbors: +C (=+128) for
// x+1, +WOUT*C (=+32768) for y+1.

__global__ __launch_bounds__(256) void unpool_gather_kernel(
    const float4* __restrict__ upd4,
    const int4* __restrict__ mask4,
    float* __restrict__ out) {
    const int t = blockIdx.x * blockDim.x + threadIdx.x;   // 0 .. B*H*W*C/4-1

    // t indexes groups of 4 channels: c4 = t & 31, w = (t>>5)&127,
    // h = (t>>12)&127, b = t>>19.
    const int c = (t & 31) << 2;
    const int w = (t >> 5) & 127;
    const int h = (t >> 12) & 127;
    const int b = t >> 19;

    const int4   m = mask4[t];
    const float4 u = upd4[t];

    const int e00 = (h << 16) | (w << 8) | c;        // within-batch offset, corner (2h,2w)
    float* const o = out + (((long long)b) << 23) + e00;

    float4 r;

    // (2h, 2w)
    r.x = (m.x == e00 + 0) ? u.x : 0.0f;
    r.y = (m.y == e00 + 1) ? u.y : 0.0f;
    r.z = (m.z == e00 + 2) ? u.z : 0.0f;
    r.w = (m.w == e00 + 3) ? u.w : 0.0f;
    *reinterpret_cast<float4*>(o) = r;

    // (2h, 2w+1)
    const int e01 = e00 + 128;
    r.x = (m.x == e01 + 0) ? u.x : 0.0f;
    r.y = (m.y == e01 + 1) ? u.y : 0.0f;
    r.z = (m.z == e01 + 2) ? u.z : 0.0f;
    r.w = (m.w == e01 + 3) ? u.w : 0.0f;
    *reinterpret_cast<float4*>(o + 128) = r;

    // (2h+1, 2w)
    const int e10 = e00 + 32768;
    r.x = (m.x == e10 + 0) ? u.x : 0.0f;
    r.y = (m.y == e10 + 1) ? u.y : 0.0f;
    r.z = (m.z == e10 + 2) ? u.z : 0.0f;
    r.w = (m.w == e10 + 3) ? u.w : 0.0f;
    *reinterpret_cast<float4*>(o + 32768) = r;

    // (2h+1, 2w+1)
    const int e11 = e10 + 128;
    r.x = (m.x == e11 + 0) ? u.x : 0.0f;
    r.y = (m.y == e11 + 1) ? u.y : 0.0f;
    r.z = (m.z == e11 + 2) ? u.z : 0.0f;
    r.w = (m.w == e11 + 3) ? u.w : 0.0f;
    *reinterpret_cast<float4*>(o + 32768 + 128) = r;
}

extern "C" void kernel_launch(void* const* d_in, const int* in_sizes, int n_in,
                              void* d_out, int out_size, void* d_ws, size_t ws_size,
                              hipStream_t stream) {
    const float4* upd4  = reinterpret_cast<const float4*>(d_in[0]);
    const int4*   mask4 = reinterpret_cast<const int4*>(d_in[1]);
    float*        out   = reinterpret_cast<float*>(d_out);

    const int n_in_elems = in_sizes[0];          // B*H*W*C = 16,777,216
    const int n_threads  = n_in_elems / 4;       // 4,194,304
    const int block      = 256;
    const int grid       = n_threads / block;    // 16384

    unpool_gather_kernel<<<grid, block, 0, stream>>>(upd4, mask4, out);
}

// Round 3
// 348.623 us; speedup vs baseline: 1.0283x; 1.0283x over previous
//
#include <hip/hip_runtime.h>
#include <hip/hip_bf16.h>

// MaxUnpooling2D as a pure gather (see R0 notes).
// setup_inputs guarantees mask[b,h,w,c] = ((2h+dy)*WOUT + (2w+dx))*C + c with
// dy,dx in {0,1}: window-local, channel-preserving, duplicate-free scatter.
// Inverted to a gather: output (b,yo,xo,c) = updates[b,yo/2,xo/2,c] iff
// mask[b,yo/2,xo/2,c] == (yo*WOUT+xo)*C + c, else 0. Every output element is
// written exactly once (overwrites the 0xAA poison), no atomics, no zero-fill.
//
// R1/R2 change: all global accesses nontemporal — inputs read once, output
// written once; caching them only thrashes the 32 MiB L2. R2 fix: use clang
// ext_vector_type instead of HIP float4/int4 (classes) — the nontemporal
// builtins only accept scalar/clang-vector pointees.
// Traffic floor: 128 MiB read + 256 MiB write = 402 MB ≈ 63 us @ 6.4 TB/s.
//
// Shapes (powers of 2): B=8, H=W=128, C=128, HOUT=WOUT=256.
// Within-batch output offset of window corner (2h,2w,c) = h<<16 | w<<8 | c ==
// the mask encoding with dy=dx=0. Neighbors: +128 floats (x+1), +32768 (y+1).

typedef float fx4 __attribute__((ext_vector_type(4)));
typedef int   ix4 __attribute__((ext_vector_type(4)));

__global__ __launch_bounds__(256) void unpool_gather_kernel(
    const fx4* __restrict__ upd4,
    const ix4* __restrict__ mask4,
    float* __restrict__ out) {
    const int t = blockIdx.x * blockDim.x + threadIdx.x;   // 0 .. B*H*W*C/4-1

    // t -> (b,h,w,c4):  c = (t&31)*4, w = (t>>5)&127, h = (t>>12)&127, b = t>>19
    const int c = (t & 31) << 2;
    const int w = (t >> 5) & 127;
    const int h = (t >> 12) & 127;
    const int b = t >> 19;

    const ix4 m = __builtin_nontemporal_load(mask4 + t);
    const fx4 u = __builtin_nontemporal_load(upd4 + t);

    const int e00 = (h << 16) | (w << 8) | c;  // within-batch offset of (2h,2w,c)
    float* const o = out + (((long long)b) << 23) + e00;

    fx4 r;

    // (2h, 2w)
    r.x = (m.x == e00 + 0) ? u.x : 0.0f;
    r.y = (m.y == e00 + 1) ? u.y : 0.0f;
    r.z = (m.z == e00 + 2) ? u.z : 0.0f;
    r.w = (m.w == e00 + 3) ? u.w : 0.0f;
    __builtin_nontemporal_store(r, reinterpret_cast<fx4*>(o));

    // (2h, 2w+1)
    const int e01 = e00 + 128;
    r.x = (m.x == e01 + 0) ? u.x : 0.0f;
    r.y = (m.y == e01 + 1) ? u.y : 0.0f;
    r.z = (m.z == e01 + 2) ? u.z : 0.0f;
    r.w = (m.w == e01 + 3) ? u.w : 0.0f;
    __builtin_nontemporal_store(r, reinterpret_cast<fx4*>(o + 128));

    // (2h+1, 2w)
    const int e10 = e00 + 32768;
    r.x = (m.x == e10 + 0) ? u.x : 0.0f;
    r.y = (m.y == e10 + 1) ? u.y : 0.0f;
    r.z = (m.z == e10 + 2) ? u.z : 0.0f;
    r.w = (m.w == e10 + 3) ? u.w : 0.0f;
    __builtin_nontemporal_store(r, reinterpret_cast<fx4*>(o + 32768));

    // (2h+1, 2w+1)
    const int e11 = e10 + 128;
    r.x = (m.x == e11 + 0) ? u.x : 0.0f;
    r.y = (m.y == e11 + 1) ? u.y : 0.0f;
    r.z = (m.z == e11 + 2) ? u.z : 0.0f;
    r.w = (m.w == e11 + 3) ? u.w : 0.0f;
    __builtin_nontemporal_store(r, reinterpret_cast<fx4*>(o + 32768 + 128));
}

extern "C" void kernel_launch(void* const* d_in, const int* in_sizes, int n_in,
                              void* d_out, int out_size, void* d_ws, size_t ws_size,
                              hipStream_t stream) {
    const fx4* upd4  = reinterpret_cast<const fx4*>(d_in[0]);
    const ix4* mask4 = reinterpret_cast<const ix4*>(d_in[1]);
    float*     out   = reinterpret_cast<float*>(d_out);

    const int n_in_elems = in_sizes[0];          // B*H*W*C = 16,777,216
    const int n_threads  = n_in_elems / 4;       // 4,194,304
    const int block      = 256;
    const int grid       = n_threads / block;    // 16384

    unpool_gather_kernel<<<grid, block, 0, stream>>>(upd4, mask4, out);
}

// Round 4
// 346.163 us; speedup vs baseline: 1.0356x; 1.0071x over previous
//
#include <hip/hip_runtime.h>
#include <hip/hip_bf16.h>

// MaxUnpooling2D as a pure gather (see R0 notes).
// setup_inputs guarantees mask[b,h,w,c] = ((2h+dy)*WOUT + (2w+dx))*C + c with
// dy,dx in {0,1}: window-local, channel-preserving, duplicate-free scatter.
// Inverted to a gather: output (b,yo,xo,c) = updates[b,yo/2,xo/2,c] iff
// mask[b,yo/2,xo/2,c] == (yo*WOUT+xo)*C + c, else 0. Every output element is
// written exactly once (overwrites the 0xAA poison), no atomics, no zero-fill.
//
// R1-R3: all global accesses nontemporal (inputs read once, output written
// once — don't thrash L2). 358.5 -> 348.6 us.
// R4: two independent window-tiles per thread (t and t+256 within a 512-float4
// block chunk) — doubles per-wave memory-level parallelism, halves waitcnt
// frequency per byte. All accesses remain wave-contiguous 512 B/instr with
// fully-covered 64 B lines.
// Traffic floor: 128 MiB read + 256 MiB write = 402 MB ~= 73-80 us at
// realistic mixed-stream BW; harness poison/restore overhead ~248 us is fixed.
//
// Shapes (powers of 2): B=8, H=W=128, C=128, HOUT=WOUT=256.
// Within-batch output offset of window corner (2h,2w,c) = h<<16 | w<<8 | c ==
// the mask encoding with dy=dx=0. Neighbors: +128 floats (x+1), +32768 (y+1).

typedef float fx4 __attribute__((ext_vector_type(4)));
typedef int   ix4 __attribute__((ext_vector_type(4)));

__device__ __forceinline__ void do_tile(const fx4* __restrict__ upd4,
                                        const ix4* __restrict__ mask4,
                                        float* __restrict__ out, int t) {
    // t -> (b,h,w,c4):  c = (t&31)*4, w = (t>>5)&127, h = (t>>12)&127, b = t>>19
    const int c = (t & 31) << 2;
    const int w = (t >> 5) & 127;
    const int h = (t >> 12) & 127;
    const int b = t >> 19;

    const ix4 m = __builtin_nontemporal_load(mask4 + t);
    const fx4 u = __builtin_nontemporal_load(upd4 + t);

    const int e00 = (h << 16) | (w << 8) | c;  // within-batch offset of (2h,2w,c)
    float* const o = out + (((long long)b) << 23) + e00;

    fx4 r;

    // (2h, 2w)
    r.x = (m.x == e00 + 0) ? u.x : 0.0f;
    r.y = (m.y == e00 + 1) ? u.y : 0.0f;
    r.z = (m.z == e00 + 2) ? u.z : 0.0f;
    r.w = (m.w == e00 + 3) ? u.w : 0.0f;
    __builtin_nontemporal_store(r, reinterpret_cast<fx4*>(o));

    // (2h, 2w+1)
    const int e01 = e00 + 128;
    r.x = (m.x == e01 + 0) ? u.x : 0.0f;
    r.y = (m.y == e01 + 1) ? u.y : 0.0f;
    r.z = (m.z == e01 + 2) ? u.z : 0.0f;
    r.w = (m.w == e01 + 3) ? u.w : 0.0f;
    __builtin_nontemporal_store(r, reinterpret_cast<fx4*>(o + 128));

    // (2h+1, 2w)
    const int e10 = e00 + 32768;
    r.x = (m.x == e10 + 0) ? u.x : 0.0f;
    r.y = (m.y == e10 + 1) ? u.y : 0.0f;
    r.z = (m.z == e10 + 2) ? u.z : 0.0f;
    r.w = (m.w == e10 + 3) ? u.w : 0.0f;
    __builtin_nontemporal_store(r, reinterpret_cast<fx4*>(o + 32768));

    // (2h+1, 2w+1)
    const int e11 = e10 + 128;
    r.x = (m.x == e11 + 0) ? u.x : 0.0f;
    r.y = (m.y == e11 + 1) ? u.y : 0.0f;
    r.z = (m.z == e11 + 2) ? u.z : 0.0f;
    r.w = (m.w == e11 + 3) ? u.w : 0.0f;
    __builtin_nontemporal_store(r, reinterpret_cast<fx4*>(o + 32768 + 128));
}

__global__ __launch_bounds__(256) void unpool_gather_kernel(
    const fx4* __restrict__ upd4,
    const ix4* __restrict__ mask4,
    float* __restrict__ out) {
    // Each block owns a chunk of 512 consecutive float4s; each thread handles
    // two wave-contiguous tiles 256 apart (independent -> 2x MLP per wave).
    const int base = blockIdx.x * 512 + threadIdx.x;
    do_tile(upd4, mask4, out, base);
    do_tile(upd4, mask4, out, base + 256);
}

extern "C" void kernel_launch(void* const* d_in, const int* in_sizes, int n_in,
                              void* d_out, int out_size, void* d_ws, size_t ws_size,
                              hipStream_t stream) {
    const fx4* upd4  = reinterpret_cast<const fx4*>(d_in[0]);
    const ix4* mask4 = reinterpret_cast<const ix4*>(d_in[1]);
    float*     out   = reinterpret_cast<float*>(d_out);

    const int n_in_elems = in_sizes[0];          // B*H*W*C = 16,777,216
    const int n_float4   = n_in_elems / 4;       // 4,194,304
    const int block      = 256;
    const int grid       = n_float4 / (block * 2);  // 8192

    unpool_gather_kernel<<<grid, block, 0, stream>>>(upd4, mask4, out);
}